// Round 6
// baseline (670.761 us; speedup 1.0000x reference)
//
#include <hip/hip_runtime.h>
#include <hip/hip_bf16.h>

// Problem sizes (fixed)
#define B_SZ 131072
#define F_SZ 784
#define H_SZ 392
#define D_SZ 28
#define K_SZ 512
#define HSTR 424   // hs row stride in shorts
#define BM   128
#define NBLK (B_SZ / BM)   // 1024

typedef __attribute__((ext_vector_type(8))) short short8v;
typedef __attribute__((ext_vector_type(4))) float f32x4;

__device__ inline short f2bf(float f) {
  __hip_bfloat16 h = __float2bfloat16(f);
  return __builtin_bit_cast(short, h);
}

__device__ inline void glds16(const short* src, short* dst) {
  __builtin_amdgcn_global_load_lds(
      (const __attribute__((address_space(1))) unsigned int*)src,
      (__attribute__((address_space(3))) unsigned int*)dst, 16, 0, 0);
}

__device__ inline int swz4(int r) { return (r & 3) ^ ((r >> 2) & 3); }

// ws layout (float offsets)
#define WS_PN2   401408
#define WS_P1    532992
#define WS_PR    535040
#define WS_W1T   537088
#define WS_W2T   716288
#define WS_M2P   722944

// ---------------------------------------------------------------------------
// Decoder table: x_rec_table[k] = relu(prior[k]@W3+b3)@W4 + b4 ; pn2[k]
// ---------------------------------------------------------------------------
__global__ __launch_bounds__(256) void precompute_kernel(
    const float* __restrict__ W3, const float* __restrict__ b3,
    const float* __restrict__ W4, const float* __restrict__ b4,
    const float* __restrict__ prior,
    float* __restrict__ table, float* __restrict__ pn2) {
  __shared__ float ps[D_SZ];
  __shared__ float h2s[H_SZ];
  const int k = blockIdx.x;
  const int t = threadIdx.x;
  if (t < D_SZ) ps[t] = prior[k * D_SZ + t];
  __syncthreads();
  for (int j = t; j < H_SZ; j += 256) {
    float acc = b3[j];
    #pragma unroll
    for (int d = 0; d < D_SZ; ++d) acc += ps[d] * W3[d * H_SZ + j];
    h2s[j] = fmaxf(acc, 0.f);
  }
  if (t == 0) {
    float s = 0.f;
    #pragma unroll
    for (int d = 0; d < D_SZ; ++d) s += ps[d] * ps[d];
    pn2[k] = s;
  }
  __syncthreads();
  for (int f = t; f < F_SZ; f += 256) {
    float acc = b4[f];
    for (int j = 0; j < H_SZ; ++j) acc += h2s[j] * W4[j * F_SZ + f];
    table[(size_t)k * F_SZ + f] = acc;
  }
}

// ---------------------------------------------------------------------------
// W1T[c][k] = bf16(W1[k][c]), [448][800], zero-padded. LDS-tiled transpose.
// ---------------------------------------------------------------------------
__global__ __launch_bounds__(256) void w1t_kernel(const float* __restrict__ W1,
                                                  short* __restrict__ W1T) {
  __shared__ float tile[64][65];
  const int k0 = blockIdx.x * 64;
  const int c0 = blockIdx.y * 64;
  const int t = threadIdx.x;
  for (int i = t; i < 4096; i += 256) {
    const int kk = i >> 6, cc = i & 63;
    const int k = k0 + kk, c = c0 + cc;
    tile[kk][cc] = (k < F_SZ && c < H_SZ) ? W1[(size_t)k * H_SZ + c] : 0.f;
  }
  __syncthreads();
  for (int i = t; i < 4096; i += 256) {
    const int cc = i >> 6, kk = i & 63;
    const int k = k0 + kk, c = c0 + cc;
    if (k < 800) W1T[(size_t)c * 800 + k] = f2bf(tile[kk][cc]);
  }
}

// ---------------------------------------------------------------------------
// W2T[d][j] = bf16(W2[j][d]) [32][416] ; M2P[c][d] = bf16(-2*prior[c][d]) [512][32]
// ---------------------------------------------------------------------------
__global__ __launch_bounds__(256) void prep2_kernel(
    const float* __restrict__ W2, const float* __restrict__ prior,
    short* __restrict__ W2T, short* __restrict__ M2P) {
  const int i = blockIdx.x * 256 + threadIdx.x;
  if (i < 32 * 416) {
    const int d = i / 416, j = i % 416;
    W2T[i] = f2bf((d < D_SZ && j < H_SZ) ? W2[(size_t)j * D_SZ + d] : 0.f);
  }
  if (i < K_SZ * 32) {
    const int c = i / 32, dd = i % 32;
    M2P[i] = f2bf((dd < D_SZ) ? -2.f * prior[(size_t)c * D_SZ + dd] : 0.f);
  }
}

// ---------------------------------------------------------------------------
// Fused encoder v6: BM=128, 512 threads / 8 waves (2M x 4N), wave tile 64x112.
// Balances LDS-read pipe vs MFMA pipe (176 b128 ~ 448 MFMA per CU-step) and
// halves W L2 traffic vs BM=64. LDS 76.9KB -> 2 blocks/CU, VGPR capped 128
// (launch_bounds 512,4) -> 16 waves/CU.
//   GEMM1: h = relu(X@W1+b1); phase 2 in two 64-row halves: z = h@W2+b2;
//   phase 3: distances via MFMA, argmin; loss1 = min distance;
//   fused loss_rec via X re-read (L2/L3-local).
// ---------------------------------------------------------------------------
union XZ {
  short Xs[2][BM][32];    // 16,384 B  bf16 X tiles, granule-swizzled
  short zs[BM][32];       // 8,192 B   bf16 z (phase >=2; Xs dead)
};
union WH {
  short Ws[2][448 * 32];  // 57,344 B  staged W1T chunk, double-buffered
  short hs[64][HSTR];     // 54,272 B  bf16 h half-tile
};

__global__ __launch_bounds__(512, 4) void encoder_kernel(
    const float* __restrict__ X, const short* __restrict__ W1T,
    const float* __restrict__ b1, const short* __restrict__ W2T,
    const float* __restrict__ b2, const short* __restrict__ M2P,
    const float* __restrict__ pn2, const float* __restrict__ table,
    float* __restrict__ partial1, float* __restrict__ partialR) {
  __shared__ XZ xz;
  __shared__ WH wh;
  __shared__ float pn2s[K_SZ];      // 2,048 B
  __shared__ float zn2p[2][BM];     // 1,024 B
  __shared__ float red1[8], redR[8];

  const int t = threadIdx.x;
  const int w = t >> 6;        // wave 0..7
  const int l = t & 63;
  const int lr = l & 15;
  const int lg = l >> 4;       // 0..3
  const int wm = w >> 2;       // M-half: rows wm*64..
  const int wn = w & 3;        // N-quarter: cols wn*112..
  const int row0 = blockIdx.x * BM;

  f32x4 acc[4][7];
  #pragma unroll
  for (int mt = 0; mt < 4; ++mt)
    #pragma unroll
    for (int nt = 0; nt < 7; ++nt) acc[mt][nt] = (f32x4){0.f, 0.f, 0.f, 0.f};

  pn2s[t] = pn2[t];

  // X staging roles: 512 threads cover 128 rows x 4 col-groups (8 cols each)
  const int sr = t >> 2;        // 0..127
  const int sg = t & 3;         // 0..3
  const int sslot = (sg ^ swz4(sr)) * 8;
  const float* xrow = X + (size_t)(row0 + sr) * F_SZ;

  // ---- prologue: stage W(0) + X(0), full drain once ----
  for (int ci = w; ci < 28; ci += 8) {
    const int c = ci * 16 + (l >> 2);
    const int srcg = (l & 3) ^ swz4(c);
    glds16(W1T + (size_t)c * 800 + 8 * srcg, &wh.Ws[0][ci * 512]);
  }
  {
    const float4 xa = *(const float4*)(xrow + sg * 8);
    const float4 xc = *(const float4*)(xrow + sg * 8 + 4);
    short8v pk;
    pk[0] = f2bf(xa.x); pk[1] = f2bf(xa.y); pk[2] = f2bf(xa.z); pk[3] = f2bf(xa.w);
    pk[4] = f2bf(xc.x); pk[5] = f2bf(xc.y); pk[6] = f2bf(xc.z); pk[7] = f2bf(xc.w);
    *(short8v*)&xz.Xs[0][sr][sslot] = pk;
  }
  __syncthreads();

  // ---- GEMM1 main loop: 25 K-steps of 32, double-buffered ----
  for (int ks = 0; ks < 25; ++ks) {
    const int cur = ks & 1, nxt = cur ^ 1;
    short8v pk;
    bool have_x = false;
    if (ks < 24) {
      const int k0n = (ks + 1) * 32;
      for (int ci = w; ci < 28; ci += 8) {
        const int c = ci * 16 + (l >> 2);
        const int srcg = (l & 3) ^ swz4(c);
        glds16(W1T + (size_t)c * 800 + k0n + 8 * srcg, &wh.Ws[nxt][ci * 512]);
      }
      const int kg = k0n + sg * 8;
      float4 xa = {0.f, 0.f, 0.f, 0.f}, xc = {0.f, 0.f, 0.f, 0.f};
      if (kg < F_SZ) {
        xa = *(const float4*)(xrow + kg);
        xc = *(const float4*)(xrow + kg + 4);
      }
      pk[0] = f2bf(xa.x); pk[1] = f2bf(xa.y); pk[2] = f2bf(xa.z); pk[3] = f2bf(xa.w);
      pk[4] = f2bf(xc.x); pk[5] = f2bf(xc.y); pk[6] = f2bf(xc.z); pk[7] = f2bf(xc.w);
      have_x = true;
    }
    // compute current tile: 4 mt x 7 nt MFMA
    short8v afr[4];
    #pragma unroll
    for (int mt = 0; mt < 4; ++mt) {
      const int row = wm * 64 + mt * 16 + lr;
      const int g2 = lg ^ swz4(row);
      afr[mt] = *(const short8v*)&xz.Xs[cur][row][g2 * 8];
    }
    #pragma unroll
    for (int nt = 0; nt < 7; ++nt) {
      const int c = wn * 112 + nt * 16 + lr;
      const int tg = lg ^ swz4(c);
      const short8v bfr = *(const short8v*)&wh.Ws[cur][c * 32 + tg * 8];
      #pragma unroll
      for (int mt = 0; mt < 4; ++mt)
        acc[mt][nt] = __builtin_amdgcn_mfma_f32_16x16x32_bf16(afr[mt], bfr, acc[mt][nt], 0, 0, 0);
    }
    if (have_x) {
      *(short8v*)&xz.Xs[nxt][sr][sslot] = pk;
    }
    __syncthreads();
  }

  // ---- epilogue + phase 2 in two 64-row halves ----
  float b1v[7];
  #pragma unroll
  for (int nt = 0; nt < 7; ++nt) {
    const int c = wn * 112 + nt * 16 + lr;
    b1v[nt] = (c < H_SZ) ? b1[c] : 0.f;
  }

  for (int hf = 0; hf < 2; ++hf) {
    if (wm == hf) {
      #pragma unroll
      for (int nt = 0; nt < 7; ++nt) {
        const int c = wn * 112 + nt * 16 + lr;
        if (c < 416) {
          #pragma unroll
          for (int mt = 0; mt < 4; ++mt)
            #pragma unroll
            for (int rg = 0; rg < 4; ++rg) {
              const int rL = mt * 16 + 4 * lg + rg;
              wh.hs[rL][c] = f2bf(fmaxf(acc[mt][nt][rg] + b1v[nt], 0.f));
            }
        }
      }
    }
    __syncthreads();
    // z = h@W2 + b2 on this half (8 waves: rowgrp w>>1 of 4, d-half w&1)
    {
      const int rL = (w >> 1) * 16 + lr;
      const int cD = (w & 1) * 16 + lr;
      const float b2v = (cD < D_SZ) ? b2[cD] : 0.f;
      f32x4 za = (f32x4){b2v, b2v, b2v, b2v};
      #pragma unroll
      for (int ks2 = 0; ks2 < 13; ++ks2) {
        const int u = 4 * ks2 + lg;
        const short8v af = *(const short8v*)&wh.hs[rL][u * 8];
        const short8v bf = *(const short8v*)&W2T[cD * 416 + ks2 * 32 + lg * 8];
        za = __builtin_amdgcn_mfma_f32_16x16x32_bf16(af, bf, za, 0, 0, 0);
      }
      #pragma unroll
      for (int rg = 0; rg < 4; ++rg) {
        float s = za[rg] * za[rg];
        s += __shfl_xor(s, 1); s += __shfl_xor(s, 2);
        s += __shfl_xor(s, 4); s += __shfl_xor(s, 8);
        const int rowG = hf * 64 + (w >> 1) * 16 + 4 * lg + rg;
        if (lr == 0) zn2p[w & 1][rowG] = s;
        const int zg = (cD >> 3) ^ swz4(rowG);
        xz.zs[rowG][zg * 8 + (cD & 7)] = f2bf(za[rg]);
      }
    }
    __syncthreads();
  }

  // ---- phase 3: d = ||z||^2 - 2 z.p + ||p||^2 via MFMA, argmin ----
  // wave w owns rows w*16 .. w*16+15 (no duplication)
  const int rowA = w * 16 + lr;
  const int gA = lg ^ swz4(rowA);
  const short8v zf = *(const short8v*)&xz.zs[rowA][gA * 8];
  float zn2r[4];
  #pragma unroll
  for (int rg = 0; rg < 4; ++rg) {
    const int row = w * 16 + 4 * lg + rg;
    zn2r[rg] = zn2p[0][row] + zn2p[1][row];
  }
  float bv[4] = {3.4e38f, 3.4e38f, 3.4e38f, 3.4e38f};
  int bi[4] = {0, 0, 0, 0};
  #pragma unroll 8
  for (int nt = 0; nt < 32; ++nt) {
    const int code = nt * 16 + lr;
    const short8v pf = *(const short8v*)&M2P[code * 32 + lg * 8];
    f32x4 dacc = (f32x4){zn2r[0], zn2r[1], zn2r[2], zn2r[3]};
    dacc = __builtin_amdgcn_mfma_f32_16x16x32_bf16(zf, pf, dacc, 0, 0, 0);
    const float pn = pn2s[code];
    #pragma unroll
    for (int rg = 0; rg < 4; ++rg) {
      const float dv = fmaxf(dacc[rg] + pn, 0.f);
      if (dv < bv[rg]) { bv[rg] = dv; bi[rg] = code; }  // ascending: first-min
    }
  }
  #pragma unroll
  for (int rg = 0; rg < 4; ++rg) {
    float v = bv[rg]; int ii = bi[rg];
    #pragma unroll
    for (int m = 1; m <= 8; m <<= 1) {
      const float ov = __shfl_xor(v, m);
      const int oi = __shfl_xor(ii, m);
      if (ov < v || (ov == v && oi < ii)) { v = ov; ii = oi; }
    }
    bv[rg] = v; bi[rg] = ii;
  }

  // loss_1 partial: min distance itself (dedupe: lane lr==0 per 16-group)
  float lsum = (lr == 0) ? (bv[0] + bv[1] + bv[2] + bv[3]) : 0.f;

  // ---- fused loss_rec: wave w's 16 rows, Sum ||x - table[idx]||^2 ----
  float racc = 0.f;
  #pragma unroll 4
  for (int rr = 0; rr < 16; ++rr) {
    const int kk = __shfl(bi[rr & 3], (rr >> 2) << 4);
    const float4* xr4 = (const float4*)&X[(size_t)(row0 + w * 16 + rr) * F_SZ];
    const float4* tr4 = (const float4*)&table[(size_t)kk * F_SZ];
    #pragma unroll
    for (int s = 0; s < 3; ++s) {
      const int i = l + 64 * s;
      const float4 xv = xr4[i], tv = tr4[i];
      const float d0 = xv.x - tv.x, d1 = xv.y - tv.y, d2 = xv.z - tv.z, d3 = xv.w - tv.w;
      racc += d0 * d0 + d1 * d1 + d2 * d2 + d3 * d3;
    }
    if (l < 4) {
      const int i = 192 + l;
      const float4 xv = xr4[i], tv = tr4[i];
      const float d0 = xv.x - tv.x, d1 = xv.y - tv.y, d2 = xv.z - tv.z, d3 = xv.w - tv.w;
      racc += d0 * d0 + d1 * d1 + d2 * d2 + d3 * d3;
    }
  }

  // ---- block reduction ----
  #pragma unroll
  for (int m = 1; m <= 32; m <<= 1) {
    lsum += __shfl_xor(lsum, m);
    racc += __shfl_xor(racc, m);
  }
  if (l == 0) { red1[w] = lsum; redR[w] = racc; }
  __syncthreads();
  if (t == 0) {
    float s1 = 0.f, sr2 = 0.f;
    #pragma unroll
    for (int i = 0; i < 8; ++i) { s1 += red1[i]; sr2 += redR[i]; }
    partial1[blockIdx.x] = s1;
    partialR[blockIdx.x] = sr2;
  }
}

// ---------------------------------------------------------------------------
// Final: loss = (0.625*s1 + srec)/B   (loss_1 == loss_2 forward; 1.25*0.5)
// ---------------------------------------------------------------------------
__global__ __launch_bounds__(256) void final_kernel(
    const float* __restrict__ partial1, const float* __restrict__ partialR,
    float* __restrict__ out) {
  __shared__ float s1s[256], srs[256];
  const int t = threadIdx.x;
  float s1 = 0.f, sr = 0.f;
  for (int i = t; i < NBLK; i += 256) s1 += partial1[i];
  for (int i = t; i < NBLK; i += 256) sr += partialR[i];
  s1s[t] = s1; srs[t] = sr;
  __syncthreads();
  for (int off = 128; off > 0; off >>= 1) {
    if (t < off) { s1s[t] += s1s[t + off]; srs[t] += srs[t + off]; }
    __syncthreads();
  }
  if (t == 0) out[0] = (0.625f * s1s[0] + srs[0]) * (1.0f / (float)B_SZ);
}

extern "C" void kernel_launch(void* const* d_in, const int* in_sizes, int n_in,
                              void* d_out, int out_size, void* d_ws, size_t ws_size,
                              hipStream_t stream) {
  const float* X     = (const float*)d_in[0];
  const float* W1    = (const float*)d_in[1];
  const float* b1    = (const float*)d_in[2];
  const float* W2    = (const float*)d_in[3];
  const float* b2    = (const float*)d_in[4];
  const float* W3    = (const float*)d_in[5];
  const float* b3    = (const float*)d_in[6];
  const float* W4    = (const float*)d_in[7];
  const float* b4    = (const float*)d_in[8];
  const float* prior = (const float*)d_in[9];

  float* wsf   = (float*)d_ws;
  float* table = wsf;
  float* pn2   = wsf + WS_PN2;
  float* part1 = wsf + WS_P1;
  float* partR = wsf + WS_PR;
  short* W1T   = (short*)(wsf + WS_W1T);
  short* W2T   = (short*)(wsf + WS_W2T);
  short* M2P   = (short*)(wsf + WS_M2P);
  float* out   = (float*)d_out;

  precompute_kernel<<<dim3(K_SZ), dim3(256), 0, stream>>>(W3, b3, W4, b4, prior, table, pn2);
  w1t_kernel<<<dim3(13, 7), dim3(256), 0, stream>>>(W1, W1T);
  prep2_kernel<<<dim3(64), dim3(256), 0, stream>>>(W2, prior, W2T, M2P);
  encoder_kernel<<<dim3(NBLK), dim3(512), 0, stream>>>(
      X, W1T, b1, W2T, b2, M2P, pn2, table, part1, partR);
  final_kernel<<<dim3(1), dim3(256), 0, stream>>>(part1, partR, out);
}

// Round 7
// 370.060 us; speedup vs baseline: 1.8126x; 1.8126x over previous
//
#include <hip/hip_runtime.h>
#include <hip/hip_bf16.h>

// Problem sizes (fixed)
#define B_SZ 131072
#define F_SZ 784
#define H_SZ 392
#define D_SZ 28
#define K_SZ 512
#define HSTR 424   // hs row stride in shorts (848B -> 2-way-max bank spread)
#define NBLK 2048  // B_SZ / 64

typedef __attribute__((ext_vector_type(8))) short short8v;
typedef __attribute__((ext_vector_type(4))) float f32x4;

__device__ inline short f2bf(float f) {
  __hip_bfloat16 h = __float2bfloat16(f);
  return __builtin_bit_cast(short, h);
}

__device__ inline int swz4(int r) { return (r & 3) ^ ((r >> 2) & 3); }

// ws layout (float offsets)
#define WS_PN2   401408
#define WS_P1    532992
#define WS_PR    535040
#define WS_W1T   537088
#define WS_W2T   716288
#define WS_M2P   722944

// ---------------------------------------------------------------------------
// Decoder table: x_rec_table[k] = relu(prior[k]@W3+b3)@W4 + b4 ; pn2[k]
// ---------------------------------------------------------------------------
__global__ __launch_bounds__(256) void precompute_kernel(
    const float* __restrict__ W3, const float* __restrict__ b3,
    const float* __restrict__ W4, const float* __restrict__ b4,
    const float* __restrict__ prior,
    float* __restrict__ table, float* __restrict__ pn2) {
  __shared__ float ps[D_SZ];
  __shared__ float h2s[H_SZ];
  const int k = blockIdx.x;
  const int t = threadIdx.x;
  if (t < D_SZ) ps[t] = prior[k * D_SZ + t];
  __syncthreads();
  for (int j = t; j < H_SZ; j += 256) {
    float acc = b3[j];
    #pragma unroll
    for (int d = 0; d < D_SZ; ++d) acc += ps[d] * W3[d * H_SZ + j];
    h2s[j] = fmaxf(acc, 0.f);
  }
  if (t == 0) {
    float s = 0.f;
    #pragma unroll
    for (int d = 0; d < D_SZ; ++d) s += ps[d] * ps[d];
    pn2[k] = s;
  }
  __syncthreads();
  for (int f = t; f < F_SZ; f += 256) {
    float acc = b4[f];
    for (int j = 0; j < H_SZ; ++j) acc += h2s[j] * W4[j * F_SZ + f];
    table[(size_t)k * F_SZ + f] = acc;
  }
}

// ---------------------------------------------------------------------------
// W1T[c][k] = bf16(W1[k][c]), [448][800], zero-padded. LDS-tiled transpose.
// ---------------------------------------------------------------------------
__global__ __launch_bounds__(256) void w1t_kernel(const float* __restrict__ W1,
                                                  short* __restrict__ W1T) {
  __shared__ float tile[64][65];
  const int k0 = blockIdx.x * 64;
  const int c0 = blockIdx.y * 64;
  const int t = threadIdx.x;
  for (int i = t; i < 4096; i += 256) {
    const int kk = i >> 6, cc = i & 63;
    const int k = k0 + kk, c = c0 + cc;
    tile[kk][cc] = (k < F_SZ && c < H_SZ) ? W1[(size_t)k * H_SZ + c] : 0.f;
  }
  __syncthreads();
  for (int i = t; i < 4096; i += 256) {
    const int cc = i >> 6, kk = i & 63;
    const int k = k0 + kk, c = c0 + cc;
    if (k < 800) W1T[(size_t)c * 800 + k] = f2bf(tile[kk][cc]);
  }
}

// ---------------------------------------------------------------------------
// W2T[d][j] = bf16(W2[j][d]) [32][416] ; M2P[c][d] = bf16(-2*prior[c][d]) [512][32]
// ---------------------------------------------------------------------------
__global__ __launch_bounds__(256) void prep2_kernel(
    const float* __restrict__ W2, const float* __restrict__ prior,
    short* __restrict__ W2T, short* __restrict__ M2P) {
  const int i = blockIdx.x * 256 + threadIdx.x;
  if (i < 32 * 416) {
    const int d = i / 416, j = i % 416;
    W2T[i] = f2bf((d < D_SZ && j < H_SZ) ? W2[(size_t)j * D_SZ + d] : 0.f);
  }
  if (i < K_SZ * 32) {
    const int c = i / 32, dd = i % 32;
    M2P[i] = f2bf((dd < D_SZ) ? -2.f * prior[(size_t)c * D_SZ + dd] : 0.f);
  }
}

// ---------------------------------------------------------------------------
// Fused encoder v7: B-fragments in registers (dbuf, prefetch-1 from L2),
// X via small ring-3 LDS tile (prefetch ~2.5 steps, covers HBM latency),
// raw s_barrier + lgkmcnt(0) only -- VMEM prefetches stay in flight across
// barriers (compiler def-use inserts exact counted vmcnt before uses).
// 256 threads / 4 waves, 1M x 4N, wave tile 64x112, acc[4][7].
// LDS ~73KB -> 2 blocks/CU; VGPR ~240 (launch_bounds 256,2) -> 2 waves/SIMD.
// ---------------------------------------------------------------------------
#define GSTEP(K, BCUR, BNXT, XHA, XHC, DO_B, DO_XW, DO_XL) do {               \
    if (DO_B) {                                                               \
      _Pragma("unroll")                                                       \
      for (int nt_ = 0; nt_ < 7; ++nt_)                                       \
        BNXT[nt_] = *(const short8v*)(wbp + (size_t)nt_ * (16 * 800) +        \
                                      ((K) + 1) * 32);                        \
    }                                                                         \
    if (DO_XW) {                                                              \
      short8v pk_;                                                            \
      pk_[0] = f2bf(XHA.x); pk_[1] = f2bf(XHA.y);                             \
      pk_[2] = f2bf(XHA.z); pk_[3] = f2bf(XHA.w);                             \
      pk_[4] = f2bf(XHC.x); pk_[5] = f2bf(XHC.y);                             \
      pk_[6] = f2bf(XHC.z); pk_[7] = f2bf(XHC.w);                             \
      *(short8v*)&Xs[((K) + 1) % 3][sr][sslot] = pk_;                         \
    }                                                                         \
    short8v afr_[4];                                                          \
    _Pragma("unroll")                                                         \
    for (int mt_ = 0; mt_ < 4; ++mt_) {                                       \
      const int row_ = mt_ * 16 + lr;                                         \
      const int g2_ = lg ^ swz4(row_);                                        \
      afr_[mt_] = *(const short8v*)&Xs[(K) % 3][row_][g2_ * 8];               \
    }                                                                         \
    if (DO_XL) {                                                              \
      const int kg_ = ((K) + 3) * 32 + sg * 8;                                \
      XHA = (float4){0.f, 0.f, 0.f, 0.f};                                     \
      XHC = (float4){0.f, 0.f, 0.f, 0.f};                                     \
      if (kg_ < F_SZ) {                                                       \
        XHA = *(const float4*)(xrow + kg_);                                   \
        XHC = *(const float4*)(xrow + kg_ + 4);                               \
      }                                                                       \
    }                                                                         \
    _Pragma("unroll")                                                         \
    for (int nt_ = 0; nt_ < 7; ++nt_) {                                       \
      _Pragma("unroll")                                                       \
      for (int mt_ = 0; mt_ < 4; ++mt_)                                       \
        acc[mt_][nt_] = __builtin_amdgcn_mfma_f32_16x16x32_bf16(              \
            afr_[mt_], BCUR[nt_], acc[mt_][nt_], 0, 0, 0);                    \
    }                                                                         \
    asm volatile("s_waitcnt lgkmcnt(0)" ::: "memory");                        \
    __builtin_amdgcn_s_barrier();                                             \
  } while (0)

__global__ __launch_bounds__(256, 2) void encoder_kernel(
    const float* __restrict__ X, const short* __restrict__ W1T,
    const float* __restrict__ b1, const short* __restrict__ W2T,
    const float* __restrict__ b2, const short* __restrict__ M2P,
    const float* __restrict__ pn2, const float* __restrict__ table,
    float* __restrict__ partial1, float* __restrict__ partialR) {
  __shared__ short Xs[3][64][32];   // 12,288 B  bf16 X tiles, ring-3, swizzled
  __shared__ short hs[64][HSTR];    // 54,272 B  bf16 h tile
  __shared__ short zs[64][32];      // 4,096 B   bf16 z, granule-swizzled
  __shared__ float pn2s[K_SZ];      // 2,048 B
  __shared__ float zn2p[2][64];     // 512 B
  __shared__ float red1[4], redR[4];

  const int t = threadIdx.x;
  const int w = t >> 6;        // wave 0..3 (N-quarter in GEMM1)
  const int l = t & 63;
  const int lr = l & 15;
  const int lg = l >> 4;       // 0..3
  const int row0 = blockIdx.x * 64;

  f32x4 acc[4][7];
  #pragma unroll
  for (int mt = 0; mt < 4; ++mt)
    #pragma unroll
    for (int nt = 0; nt < 7; ++nt) acc[mt][nt] = (f32x4){0.f, 0.f, 0.f, 0.f};

  // X staging roles: 256 threads cover 64 rows x 4 col-groups (8 cols each)
  const int sr = t >> 2;        // 0..63
  const int sg = t & 3;         // 0..3
  const int sslot = (sg ^ swz4(sr)) * 8;
  const float* xrow = X + (size_t)(row0 + sr) * F_SZ;
  // B-fragment base: this lane's W1T row (col) + lg k-subgroup
  const short* wbp = W1T + (size_t)(w * 112 + lr) * 800 + lg * 8;

  short8v bA[7], bB[7];
  float4 x0a, x0c, x1a, x1c;

  for (int i = t; i < K_SZ; i += 256) pn2s[i] = pn2[i];

  // ---- prologue: X(0)->LDS, B(0)->bA, X(1)->slot1, X(2)->slot0 ----
  {
    const float4 a0 = *(const float4*)(xrow + sg * 8);
    const float4 c0 = *(const float4*)(xrow + sg * 8 + 4);
    #pragma unroll
    for (int nt = 0; nt < 7; ++nt)
      bA[nt] = *(const short8v*)(wbp + (size_t)nt * (16 * 800));
    x1a = *(const float4*)(xrow + 32 + sg * 8);
    x1c = *(const float4*)(xrow + 36 + sg * 8);
    short8v pk;
    pk[0] = f2bf(a0.x); pk[1] = f2bf(a0.y); pk[2] = f2bf(a0.z); pk[3] = f2bf(a0.w);
    pk[4] = f2bf(c0.x); pk[5] = f2bf(c0.y); pk[6] = f2bf(c0.z); pk[7] = f2bf(c0.w);
    *(short8v*)&Xs[0][sr][sslot] = pk;
    x0a = *(const float4*)(xrow + 64 + sg * 8);
    x0c = *(const float4*)(xrow + 68 + sg * 8);
    asm volatile("s_waitcnt lgkmcnt(0)" ::: "memory");
    __builtin_amdgcn_s_barrier();
  }

  // ---- GEMM1 main loop: steps 0..21 as 11 double-steps, then 22,23,24 ----
  for (int j = 0; j < 11; ++j) {
    const int k0 = 2 * j;
    GSTEP(k0,     bA, bB, x1a, x1c, 1, 1, 1);
    GSTEP(k0 + 1, bB, bA, x0a, x0c, 1, 1, 1);
  }
  GSTEP(22, bA, bB, x1a, x1c, 1, 1, 0);
  GSTEP(23, bB, bA, x0a, x0c, 1, 1, 0);
  GSTEP(24, bA, bB, x1a, x1c, 0, 0, 0);

  // ---- bias+relu, write h tile (bf16) ----
  float b1v[7];
  #pragma unroll
  for (int nt = 0; nt < 7; ++nt) {
    const int c = w * 112 + nt * 16 + lr;
    b1v[nt] = (c < H_SZ) ? b1[c] : 0.f;
  }
  #pragma unroll
  for (int nt = 0; nt < 7; ++nt) {
    const int c = w * 112 + nt * 16 + lr;
    if (c < 416) {
      #pragma unroll
      for (int mt = 0; mt < 4; ++mt)
        #pragma unroll
        for (int rg = 0; rg < 4; ++rg) {
          const int row = mt * 16 + 4 * lg + rg;
          hs[row][c] = f2bf(fmaxf(acc[mt][nt][rg] + b1v[nt], 0.f));
        }
    }
  }
  __syncthreads();

  // ---- phase 2: z = h@W2 + b2 (each wave: its 16 rows, 2 d-halves) ----
  f32x4 zacc[2];
  #pragma unroll
  for (int nt = 0; nt < 2; ++nt) {
    const int c = nt * 16 + lr;
    const float b2v = (c < D_SZ) ? b2[c] : 0.f;
    zacc[nt] = (f32x4){b2v, b2v, b2v, b2v};
  }
  {
    const int row = w * 16 + lr;
    #pragma unroll
    for (int ks2 = 0; ks2 < 13; ++ks2) {
      const int u = 4 * ks2 + lg;
      const short8v af = *(const short8v*)&hs[row][u * 8];
      #pragma unroll
      for (int nt = 0; nt < 2; ++nt) {
        const int c = nt * 16 + lr;
        const short8v bf = *(const short8v*)&W2T[c * 416 + ks2 * 32 + lg * 8];
        zacc[nt] = __builtin_amdgcn_mfma_f32_16x16x32_bf16(af, bf, zacc[nt], 0, 0, 0);
      }
    }
  }

  // zn2 per C-row + write z (bf16) for phase-3 A-fragments
  #pragma unroll
  for (int rg = 0; rg < 4; ++rg) {
    float s = zacc[0][rg] * zacc[0][rg] + zacc[1][rg] * zacc[1][rg];
    s += __shfl_xor(s, 1); s += __shfl_xor(s, 2);
    s += __shfl_xor(s, 4); s += __shfl_xor(s, 8);
    const int row = w * 16 + 4 * lg + rg;
    if (lr == 0) { zn2p[0][row] = s; zn2p[1][row] = 0.f; }
  }
  #pragma unroll
  for (int nt = 0; nt < 2; ++nt)
    #pragma unroll
    for (int rg = 0; rg < 4; ++rg) {
      const int row = w * 16 + 4 * lg + rg;
      const int c = nt * 16 + lr;
      const int zg = (c >> 3) ^ swz4(row);
      zs[row][zg * 8 + (c & 7)] = f2bf(zacc[nt][rg]);
    }
  __syncthreads();

  // ---- phase 3: d = ||z||^2 - 2 z.p + ||p||^2 via MFMA, argmin ----
  const int rowA = w * 16 + lr;
  const int gA = lg ^ swz4(rowA);
  const short8v zf = *(const short8v*)&zs[rowA][gA * 8];
  float zn2r[4];
  #pragma unroll
  for (int rg = 0; rg < 4; ++rg) {
    const int row = w * 16 + 4 * lg + rg;
    zn2r[rg] = zn2p[0][row] + zn2p[1][row];
  }
  float bv[4] = {3.4e38f, 3.4e38f, 3.4e38f, 3.4e38f};
  int bi[4] = {0, 0, 0, 0};
  #pragma unroll 8
  for (int nt = 0; nt < 32; ++nt) {
    const int code = nt * 16 + lr;
    const short8v pf = *(const short8v*)&M2P[code * 32 + lg * 8];
    f32x4 dacc = (f32x4){zn2r[0], zn2r[1], zn2r[2], zn2r[3]};
    dacc = __builtin_amdgcn_mfma_f32_16x16x32_bf16(zf, pf, dacc, 0, 0, 0);
    const float pn = pn2s[code];
    #pragma unroll
    for (int rg = 0; rg < 4; ++rg) {
      const float dv = fmaxf(dacc[rg] + pn, 0.f);
      if (dv < bv[rg]) { bv[rg] = dv; bi[rg] = code; }  // ascending: first-min
    }
  }
  #pragma unroll
  for (int rg = 0; rg < 4; ++rg) {
    float v = bv[rg]; int ii = bi[rg];
    #pragma unroll
    for (int m = 1; m <= 8; m <<= 1) {
      const float ov = __shfl_xor(v, m);
      const int oi = __shfl_xor(ii, m);
      if (ov < v || (ov == v && oi < ii)) { v = ov; ii = oi; }
    }
    bv[rg] = v; bi[rg] = ii;
  }

  // loss_1 partial: min distance itself (dedupe: lane lr==0 per 16-group)
  float lsum = (lr == 0) ? (bv[0] + bv[1] + bv[2] + bv[3]) : 0.f;

  // ---- fused loss_rec: wave w's 16 rows, Sum ||x - table[idx]||^2 ----
  float racc = 0.f;
  #pragma unroll 4
  for (int rr = 0; rr < 16; ++rr) {
    const int kk = __shfl(bi[rr & 3], (rr >> 2) << 4);
    const float4* xr4 = (const float4*)&X[(size_t)(row0 + w * 16 + rr) * F_SZ];
    const float4* tr4 = (const float4*)&table[(size_t)kk * F_SZ];
    #pragma unroll
    for (int s = 0; s < 3; ++s) {
      const int i = l + 64 * s;
      const float4 xv = xr4[i], tv = tr4[i];
      const float d0 = xv.x - tv.x, d1 = xv.y - tv.y, d2 = xv.z - tv.z, d3 = xv.w - tv.w;
      racc += d0 * d0 + d1 * d1 + d2 * d2 + d3 * d3;
    }
    if (l < 4) {
      const int i = 192 + l;
      const float4 xv = xr4[i], tv = tr4[i];
      const float d0 = xv.x - tv.x, d1 = xv.y - tv.y, d2 = xv.z - tv.z, d3 = xv.w - tv.w;
      racc += d0 * d0 + d1 * d1 + d2 * d2 + d3 * d3;
    }
  }

  // ---- block reduction ----
  #pragma unroll
  for (int m = 1; m <= 32; m <<= 1) {
    lsum += __shfl_xor(lsum, m);
    racc += __shfl_xor(racc, m);
  }
  if (l == 0) { red1[w] = lsum; redR[w] = racc; }
  __syncthreads();
  if (t == 0) {
    partial1[blockIdx.x] = red1[0] + red1[1] + red1[2] + red1[3];
    partialR[blockIdx.x] = redR[0] + redR[1] + redR[2] + redR[3];
  }
}

// ---------------------------------------------------------------------------
// Final: loss = (0.625*s1 + srec)/B   (loss_1 == loss_2 forward; 1.25*0.5)
// ---------------------------------------------------------------------------
__global__ __launch_bounds__(256) void final_kernel(
    const float* __restrict__ partial1, const float* __restrict__ partialR,
    float* __restrict__ out) {
  __shared__ float s1s[256], srs[256];
  const int t = threadIdx.x;
  float s1 = 0.f, sr = 0.f;
  for (int i = t; i < NBLK; i += 256) s1 += partial1[i];
  for (int i = t; i < NBLK; i += 256) sr += partialR[i];
  s1s[t] = s1; srs[t] = sr;
  __syncthreads();
  for (int off = 128; off > 0; off >>= 1) {
    if (t < off) { s1s[t] += s1s[t + off]; srs[t] += srs[t + off]; }
    __syncthreads();
  }
  if (t == 0) out[0] = (0.625f * s1s[0] + srs[0]) * (1.0f / (float)B_SZ);
}

extern "C" void kernel_launch(void* const* d_in, const int* in_sizes, int n_in,
                              void* d_out, int out_size, void* d_ws, size_t ws_size,
                              hipStream_t stream) {
  const float* X     = (const float*)d_in[0];
  const float* W1    = (const float*)d_in[1];
  const float* b1    = (const float*)d_in[2];
  const float* W2    = (const float*)d_in[3];
  const float* b2    = (const float*)d_in[4];
  const float* W3    = (const float*)d_in[5];
  const float* b3    = (const float*)d_in[6];
  const float* W4    = (const float*)d_in[7];
  const float* b4    = (const float*)d_in[8];
  const float* prior = (const float*)d_in[9];

  float* wsf   = (float*)d_ws;
  float* table = wsf;
  float* pn2   = wsf + WS_PN2;
  float* part1 = wsf + WS_P1;
  float* partR = wsf + WS_PR;
  short* W1T   = (short*)(wsf + WS_W1T);
  short* W2T   = (short*)(wsf + WS_W2T);
  short* M2P   = (short*)(wsf + WS_M2P);
  float* out   = (float*)d_out;

  precompute_kernel<<<dim3(K_SZ), dim3(256), 0, stream>>>(W3, b3, W4, b4, prior, table, pn2);
  w1t_kernel<<<dim3(13, 7), dim3(256), 0, stream>>>(W1, W1T);
  prep2_kernel<<<dim3(64), dim3(256), 0, stream>>>(W2, prior, W2T, M2P);
  encoder_kernel<<<dim3(NBLK), dim3(256), 0, stream>>>(
      X, W1T, b1, W2T, b2, M2P, pn2, table, part1, partR);
  final_kernel<<<dim3(1), dim3(256), 0, stream>>>(part1, partR, out);
}

// Round 8
// 350.787 us; speedup vs baseline: 1.9122x; 1.0549x over previous
//
#include <hip/hip_runtime.h>
#include <hip/hip_bf16.h>

// Problem sizes (fixed)
#define B_SZ 131072
#define F_SZ 784
#define H_SZ 392
#define D_SZ 28
#define K_SZ 512
#define HSTR 424    // hs row stride in shorts (848B, 212 words %32=20 -> spread)
#define BM   128
#define BK   64
#define NBLK (B_SZ / BM)   // 1024

typedef __attribute__((ext_vector_type(8))) short short8v;
typedef __attribute__((ext_vector_type(4))) float f32x4;

__device__ inline short f2bf(float f) {
  __hip_bfloat16 h = __float2bfloat16(f);
  return __builtin_bit_cast(short, h);
}

__device__ inline void glds16(const short* src, short* dst) {
  __builtin_amdgcn_global_load_lds(
      (const __attribute__((address_space(1))) unsigned int*)src,
      (__attribute__((address_space(3))) unsigned int*)dst, 16, 0, 0);
}

__device__ inline int swz4(int r) { return (r & 3) ^ ((r >> 2) & 3); }

// ws layout (float offsets)
#define WS_PN2   401408
#define WS_P1    532992
#define WS_PR    535040
#define WS_W1T   537088
#define WS_W2T   716288
#define WS_M2P   722944

// ---------------------------------------------------------------------------
// Decoder table: x_rec_table[k] = relu(prior[k]@W3+b3)@W4 + b4 ; pn2[k]
// ---------------------------------------------------------------------------
__global__ __launch_bounds__(256) void precompute_kernel(
    const float* __restrict__ W3, const float* __restrict__ b3,
    const float* __restrict__ W4, const float* __restrict__ b4,
    const float* __restrict__ prior,
    float* __restrict__ table, float* __restrict__ pn2) {
  __shared__ float ps[D_SZ];
  __shared__ float h2s[H_SZ];
  const int k = blockIdx.x;
  const int t = threadIdx.x;
  if (t < D_SZ) ps[t] = prior[k * D_SZ + t];
  __syncthreads();
  for (int j = t; j < H_SZ; j += 256) {
    float acc = b3[j];
    #pragma unroll
    for (int d = 0; d < D_SZ; ++d) acc += ps[d] * W3[d * H_SZ + j];
    h2s[j] = fmaxf(acc, 0.f);
  }
  if (t == 0) {
    float s = 0.f;
    #pragma unroll
    for (int d = 0; d < D_SZ; ++d) s += ps[d] * ps[d];
    pn2[k] = s;
  }
  __syncthreads();
  for (int f = t; f < F_SZ; f += 256) {
    float acc = b4[f];
    for (int j = 0; j < H_SZ; ++j) acc += h2s[j] * W4[j * F_SZ + f];
    table[(size_t)k * F_SZ + f] = acc;
  }
}

// ---------------------------------------------------------------------------
// W1T[c][k] = bf16(W1[k][c]), [448][800], zero-padded. LDS-tiled transpose.
// ---------------------------------------------------------------------------
__global__ __launch_bounds__(256) void w1t_kernel(const float* __restrict__ W1,
                                                  short* __restrict__ W1T) {
  __shared__ float tile[64][65];
  const int k0 = blockIdx.x * 64;
  const int c0 = blockIdx.y * 64;
  const int t = threadIdx.x;
  for (int i = t; i < 4096; i += 256) {
    const int kk = i >> 6, cc = i & 63;
    const int k = k0 + kk, c = c0 + cc;
    tile[kk][cc] = (k < F_SZ && c < H_SZ) ? W1[(size_t)k * H_SZ + c] : 0.f;
  }
  __syncthreads();
  for (int i = t; i < 4096; i += 256) {
    const int cc = i >> 6, kk = i & 63;
    const int k = k0 + kk, c = c0 + cc;
    if (k < 800) W1T[(size_t)c * 800 + k] = f2bf(tile[kk][cc]);
  }
}

// ---------------------------------------------------------------------------
// W2T[d][j] = bf16(W2[j][d]) [32][416] ; M2P[c][d] = bf16(-2*prior[c][d]) [512][32]
// ---------------------------------------------------------------------------
__global__ __launch_bounds__(256) void prep2_kernel(
    const float* __restrict__ W2, const float* __restrict__ prior,
    short* __restrict__ W2T, short* __restrict__ M2P) {
  const int i = blockIdx.x * 256 + threadIdx.x;
  if (i < 32 * 416) {
    const int d = i / 416, j = i % 416;
    W2T[i] = f2bf((d < D_SZ && j < H_SZ) ? W2[(size_t)j * D_SZ + d] : 0.f);
  }
  if (i < K_SZ * 32) {
    const int c = i / 32, dd = i % 32;
    M2P[i] = f2bf((dd < D_SZ) ? -2.f * prior[(size_t)c * D_SZ + dd] : 0.f);
  }
}

// ---------------------------------------------------------------------------
// Fused encoder v8: BM=128, BK=64, 512 threads / 8 waves (2M x 4N), 1 block/CU.
// Big K-steps: 13 barriers total; per step the 56-MFMA cluster covers the
// W-glds L2 latency so the end-of-step drain is ~free. LDS ~151KB:
//   Ws[2][448*64] (114.7KB, unions with hs[128][HSTR])
//   Xs[2][128*64] bf16 (32KB, unions with zs[128][32])
// Granule-XOR swizzle g^(row&7) on both tiles (128B rows would be 16-way
// conflicts otherwise); glds source pre-swizzled to match (rule 21).
// acc[4][7] = 112 regs/wave; launch_bounds(512,2) -> <=256 VGPR, no spill.
// ---------------------------------------------------------------------------
union WHS { short Ws[2][448 * 64]; short hs[BM][HSTR]; };
union XZS { short Xs[2][BM * 64]; short zs[BM][32]; };

__global__ __launch_bounds__(512, 2) void encoder_kernel(
    const float* __restrict__ X, const short* __restrict__ W1T,
    const float* __restrict__ b1, const short* __restrict__ W2T,
    const float* __restrict__ b2, const short* __restrict__ M2P,
    const float* __restrict__ pn2, const float* __restrict__ table,
    float* __restrict__ partial1, float* __restrict__ partialR) {
  __shared__ WHS wh;                // 114,688 B
  __shared__ XZS xz;                // 32,768 B
  __shared__ float pn2s[K_SZ];      // 2,048 B
  __shared__ float zn2s[BM];        // 512 B
  __shared__ float red1[8], redR[8];

  const int t = threadIdx.x;
  const int w = t >> 6;        // wave 0..7
  const int l = t & 63;
  const int lr = l & 15;
  const int lg = l >> 4;       // 0..3
  const int wm = w >> 2;       // M-half: rows wm*64..
  const int wn = w & 3;        // N-quarter: cols wn*112..
  const int xor7 = lr & 7;     // granule swizzle for A/B reads
  const int row0 = blockIdx.x * BM;

  f32x4 acc[4][7];
  #pragma unroll
  for (int mt = 0; mt < 4; ++mt)
    #pragma unroll
    for (int nt = 0; nt < 7; ++nt) acc[mt][nt] = (f32x4){0.f, 0.f, 0.f, 0.f};

  pn2s[t] = pn2[t];   // 512 threads, one each

  // X staging roles: thread covers (row sr2, cols sq*16..sq*16+15)
  const int sr2 = t >> 2;      // 0..127
  const int sq = t & 3;        // 0..3
  const int xsw = sr2 & 7;     // write-side granule swizzle
  const float* xrow = X + (size_t)(row0 + sr2) * F_SZ;
  // W glds roles: lane l covers row c = ci*8 + (l>>3), granule (l&7)^(l>>3)
  const int wc_sub = l >> 3;           // row within 8-row chunk
  const int wg_src = (l & 7) ^ wc_sub; // pre-swizzled source granule

  // ---- prologue: stage X(0) + W(0), drain once ----
  {
    #pragma unroll
    for (int f = 0; f < 2; ++f) {
      const float4 a = *(const float4*)(xrow + sq * 16 + f * 8);
      const float4 b = *(const float4*)(xrow + sq * 16 + f * 8 + 4);
      short8v p;
      p[0] = f2bf(a.x); p[1] = f2bf(a.y); p[2] = f2bf(a.z); p[3] = f2bf(a.w);
      p[4] = f2bf(b.x); p[5] = f2bf(b.y); p[6] = f2bf(b.z); p[7] = f2bf(b.w);
      const int pg = (2 * sq + f) ^ xsw;
      *(short8v*)&xz.Xs[0][sr2 * 64 + pg * 8] = p;
    }
    for (int ci = w; ci < 56; ci += 8) {
      const int c = ci * 8 + wc_sub;
      glds16(W1T + (size_t)c * 800 + wg_src * 8, &wh.Ws[0][ci * 512]);
    }
  }
  __syncthreads();

  // ---- GEMM1 main loop: 13 K-steps of 64 ----
  for (int ks = 0; ks < 13; ++ks) {
    const int cur = ks & 1, nxt = cur ^ 1;
    float4 xa0, xb0, xa1, xb1;
    const bool st = (ks < 12);
    if (st) {
      const int kbn = (ks + 1) * BK;
      // X loads first (oldest in vmcnt queue -> ds_write waits leave glds live)
      {
        const int kg0 = kbn + sq * 16;
        xa0 = xb0 = xa1 = xb1 = (float4){0.f, 0.f, 0.f, 0.f};
        if (kg0 < F_SZ) {           // 784 is a multiple of 16: all-or-nothing
          xa0 = *(const float4*)(xrow + kg0);
          xb0 = *(const float4*)(xrow + kg0 + 4);
          xa1 = *(const float4*)(xrow + kg0 + 8);
          xb1 = *(const float4*)(xrow + kg0 + 12);
        }
      }
      for (int ci = w; ci < 56; ci += 8) {
        const int c = ci * 8 + wc_sub;
        glds16(W1T + (size_t)c * 800 + kbn + wg_src * 8, &wh.Ws[nxt][ci * 512]);
      }
    }
    // ---- MFMA cluster: 2 k-subs x (4 A-reads + 7x(B-read + 4 MFMA)) ----
    #pragma unroll
    for (int ks2 = 0; ks2 < 2; ++ks2) {
      short8v afr[4];
      #pragma unroll
      for (int mt = 0; mt < 4; ++mt) {
        const int r = wm * 64 + mt * 16 + lr;
        const int pg = (ks2 * 4 + lg) ^ xor7;
        afr[mt] = *(const short8v*)&xz.Xs[cur][r * 64 + pg * 8];
      }
      #pragma unroll
      for (int nt = 0; nt < 7; ++nt) {
        const int c = wn * 112 + nt * 16 + lr;
        const int pg = (ks2 * 4 + lg) ^ xor7;
        const short8v bfr = *(const short8v*)&wh.Ws[cur][c * 64 + pg * 8];
        #pragma unroll
        for (int mt = 0; mt < 4; ++mt)
          acc[mt][nt] = __builtin_amdgcn_mfma_f32_16x16x32_bf16(afr[mt], bfr, acc[mt][nt], 0, 0, 0);
      }
    }
    if (st) {
      short8v p0, p1;
      p0[0] = f2bf(xa0.x); p0[1] = f2bf(xa0.y); p0[2] = f2bf(xa0.z); p0[3] = f2bf(xa0.w);
      p0[4] = f2bf(xb0.x); p0[5] = f2bf(xb0.y); p0[6] = f2bf(xb0.z); p0[7] = f2bf(xb0.w);
      p1[0] = f2bf(xa1.x); p1[1] = f2bf(xa1.y); p1[2] = f2bf(xa1.z); p1[3] = f2bf(xa1.w);
      p1[4] = f2bf(xb1.x); p1[5] = f2bf(xb1.y); p1[6] = f2bf(xb1.z); p1[7] = f2bf(xb1.w);
      const int pg0 = (2 * sq) ^ xsw;
      const int pg1 = (2 * sq + 1) ^ xsw;
      *(short8v*)&xz.Xs[nxt][sr2 * 64 + pg0 * 8] = p0;
      *(short8v*)&xz.Xs[nxt][sr2 * 64 + pg1 * 8] = p1;
    }
    __syncthreads();   // drains glds (covered by the 56-MFMA cluster) + ds ops
  }

  // ---- bias+relu, write h tile (bf16) into hs (unions over Ws) ----
  float b1v[7];
  #pragma unroll
  for (int nt = 0; nt < 7; ++nt) {
    const int c = wn * 112 + nt * 16 + lr;
    b1v[nt] = (c < H_SZ) ? b1[c] : 0.f;
  }
  #pragma unroll
  for (int nt = 0; nt < 7; ++nt) {
    const int c = wn * 112 + nt * 16 + lr;
    if (c < 416) {
      #pragma unroll
      for (int mt = 0; mt < 4; ++mt)
        #pragma unroll
        for (int rg = 0; rg < 4; ++rg) {
          const int row = wm * 64 + mt * 16 + 4 * lg + rg;
          wh.hs[row][c] = f2bf(fmaxf(acc[mt][nt][rg] + b1v[nt], 0.f));
        }
    }
  }
  __syncthreads();

  // ---- phase 2: z = h@W2 + b2 (8 waves x 16 rows, 2 d-halves each) ----
  f32x4 zacc[2];
  #pragma unroll
  for (int nt = 0; nt < 2; ++nt) {
    const int c = nt * 16 + lr;
    const float b2v = (c < D_SZ) ? b2[c] : 0.f;
    zacc[nt] = (f32x4){b2v, b2v, b2v, b2v};
  }
  {
    const int row = w * 16 + lr;
    #pragma unroll
    for (int ks2 = 0; ks2 < 13; ++ks2) {
      const int u = 4 * ks2 + lg;
      const short8v af = *(const short8v*)&wh.hs[row][u * 8];
      #pragma unroll
      for (int nt = 0; nt < 2; ++nt) {
        const int c = nt * 16 + lr;
        const short8v bf = *(const short8v*)&W2T[c * 416 + ks2 * 32 + lg * 8];
        zacc[nt] = __builtin_amdgcn_mfma_f32_16x16x32_bf16(af, bf, zacc[nt], 0, 0, 0);
      }
    }
  }

  // zn2 + write z (bf16, phase-3 layout; zs unions over Xs -- dead post-GEMM)
  #pragma unroll
  for (int rg = 0; rg < 4; ++rg) {
    float s = zacc[0][rg] * zacc[0][rg] + zacc[1][rg] * zacc[1][rg];
    s += __shfl_xor(s, 1); s += __shfl_xor(s, 2);
    s += __shfl_xor(s, 4); s += __shfl_xor(s, 8);
    const int row = w * 16 + 4 * lg + rg;
    if (lr == 0) zn2s[row] = s;
  }
  #pragma unroll
  for (int nt = 0; nt < 2; ++nt)
    #pragma unroll
    for (int rg = 0; rg < 4; ++rg) {
      const int row = w * 16 + 4 * lg + rg;
      const int c = nt * 16 + lr;
      const int zg = (c >> 3) ^ swz4(row);
      xz.zs[row][zg * 8 + (c & 7)] = f2bf(zacc[nt][rg]);
    }
  __syncthreads();

  // ---- phase 3: d = ||z||^2 - 2 z.p + ||p||^2 via MFMA, argmin ----
  const int rowA = w * 16 + lr;
  const int gA = lg ^ swz4(rowA);
  const short8v zf = *(const short8v*)&xz.zs[rowA][gA * 8];
  float zn2r[4];
  #pragma unroll
  for (int rg = 0; rg < 4; ++rg) zn2r[rg] = zn2s[w * 16 + 4 * lg + rg];
  float bv[4] = {3.4e38f, 3.4e38f, 3.4e38f, 3.4e38f};
  int bi[4] = {0, 0, 0, 0};
  #pragma unroll 8
  for (int nt = 0; nt < 32; ++nt) {
    const int code = nt * 16 + lr;
    const short8v pf = *(const short8v*)&M2P[code * 32 + lg * 8];
    f32x4 dacc = (f32x4){zn2r[0], zn2r[1], zn2r[2], zn2r[3]};
    dacc = __builtin_amdgcn_mfma_f32_16x16x32_bf16(zf, pf, dacc, 0, 0, 0);
    const float pn = pn2s[code];
    #pragma unroll
    for (int rg = 0; rg < 4; ++rg) {
      const float dv = fmaxf(dacc[rg] + pn, 0.f);
      if (dv < bv[rg]) { bv[rg] = dv; bi[rg] = code; }  // ascending: first-min
    }
  }
  #pragma unroll
  for (int rg = 0; rg < 4; ++rg) {
    float v = bv[rg]; int ii = bi[rg];
    #pragma unroll
    for (int m = 1; m <= 8; m <<= 1) {
      const float ov = __shfl_xor(v, m);
      const int oi = __shfl_xor(ii, m);
      if (ov < v || (ov == v && oi < ii)) { v = ov; ii = oi; }
    }
    bv[rg] = v; bi[rg] = ii;
  }

  // loss_1 partial: min distance itself (dedupe: lane lr==0 per 16-group)
  float lsum = (lr == 0) ? (bv[0] + bv[1] + bv[2] + bv[3]) : 0.f;

  // ---- fused loss_rec: wave w's 16 rows, Sum ||x - table[idx]||^2 ----
  float racc = 0.f;
  #pragma unroll 4
  for (int rr = 0; rr < 16; ++rr) {
    const int kk = __shfl(bi[rr & 3], (rr >> 2) << 4);
    const float4* xr4 = (const float4*)&X[(size_t)(row0 + w * 16 + rr) * F_SZ];
    const float4* tr4 = (const float4*)&table[(size_t)kk * F_SZ];
    #pragma unroll
    for (int s = 0; s < 3; ++s) {
      const int i = l + 64 * s;
      const float4 xv = xr4[i], tv = tr4[i];
      const float d0 = xv.x - tv.x, d1 = xv.y - tv.y, d2 = xv.z - tv.z, d3 = xv.w - tv.w;
      racc += d0 * d0 + d1 * d1 + d2 * d2 + d3 * d3;
    }
    if (l < 4) {
      const int i = 192 + l;
      const float4 xv = xr4[i], tv = tr4[i];
      const float d0 = xv.x - tv.x, d1 = xv.y - tv.y, d2 = xv.z - tv.z, d3 = xv.w - tv.w;
      racc += d0 * d0 + d1 * d1 + d2 * d2 + d3 * d3;
    }
  }

  // ---- block reduction ----
  #pragma unroll
  for (int m = 1; m <= 32; m <<= 1) {
    lsum += __shfl_xor(lsum, m);
    racc += __shfl_xor(racc, m);
  }
  if (l == 0) { red1[w] = lsum; redR[w] = racc; }
  __syncthreads();
  if (t == 0) {
    float s1 = 0.f, sr = 0.f;
    #pragma unroll
    for (int i = 0; i < 8; ++i) { s1 += red1[i]; sr += redR[i]; }
    partial1[blockIdx.x] = s1;
    partialR[blockIdx.x] = sr;
  }
}

// ---------------------------------------------------------------------------
// Final: loss = (0.625*s1 + srec)/B   (loss_1 == loss_2 forward; 1.25*0.5)
// ---------------------------------------------------------------------------
__global__ __launch_bounds__(256) void final_kernel(
    const float* __restrict__ partial1, const float* __restrict__ partialR,
    float* __restrict__ out) {
  __shared__ float s1s[256], srs[256];
  const int t = threadIdx.x;
  float s1 = 0.f, sr = 0.f;
  for (int i = t; i < NBLK; i += 256) s1 += partial1[i];
  for (int i = t; i < NBLK; i += 256) sr += partialR[i];
  s1s[t] = s1; srs[t] = sr;
  __syncthreads();
  for (int off = 128; off > 0; off >>= 1) {
    if (t < off) { s1s[t] += s1s[t + off]; srs[t] += srs[t + off]; }
    __syncthreads();
  }
  if (t == 0) out[0] = (0.625f * s1s[0] + srs[0]) * (1.0f / (float)B_SZ);
}

extern "C" void kernel_launch(void* const* d_in, const int* in_sizes, int n_in,
                              void* d_out, int out_size, void* d_ws, size_t ws_size,
                              hipStream_t stream) {
  const float* X     = (const float*)d_in[0];
  const float* W1    = (const float*)d_in[1];
  const float* b1    = (const float*)d_in[2];
  const float* W2    = (const float*)d_in[3];
  const float* b2    = (const float*)d_in[4];
  const float* W3    = (const float*)d_in[5];
  const float* b3    = (const float*)d_in[6];
  const float* W4    = (const float*)d_in[7];
  const float* b4    = (const float*)d_in[8];
  const float* prior = (const float*)d_in[9];

  float* wsf   = (float*)d_ws;
  float* table = wsf;
  float* pn2   = wsf + WS_PN2;
  float* part1 = wsf + WS_P1;
  float* partR = wsf + WS_PR;
  short* W1T   = (short*)(wsf + WS_W1T);
  short* W2T   = (short*)(wsf + WS_W2T);
  short* M2P   = (short*)(wsf + WS_M2P);
  float* out   = (float*)d_out;

  precompute_kernel<<<dim3(K_SZ), dim3(256), 0, stream>>>(W3, b3, W4, b4, prior, table, pn2);
  w1t_kernel<<<dim3(13, 7), dim3(256), 0, stream>>>(W1, W1T);
  prep2_kernel<<<dim3(64), dim3(256), 0, stream>>>(W2, prior, W2T, M2P);
  encoder_kernel<<<dim3(NBLK), dim3(512), 0, stream>>>(
      X, W1T, b1, W2T, b2, M2P, pn2, table, part1, partR);
  final_kernel<<<dim3(1), dim3(256), 0, stream>>>(part1, partR, out);
}